// Round 8
// baseline (254.296 us; speedup 1.0000x reference)
//
#include <hip/hip_runtime.h>
#include <math.h>

// Problem constants
#define B_    32
#define S_    2048
#define CIN_  256
#define COUT_ 256
#define K_    16
#define TOUT_ 2033   // S - K + 1

typedef __bf16 bf16x4 __attribute__((ext_vector_type(4)));
typedef __bf16 bf16x8 __attribute__((ext_vector_type(8)));
typedef float  f32x4  __attribute__((ext_vector_type(4)));

// ---------------------------------------------------------------------------
// Build B in bf16, FRAGMENT-DIRECT layout (round 8):
//   wt3[nb][j][r][e],  nb = o>>7 (o-block), j = ic*16 + k (step 0..127),
//   r = o&127 (o-local row), e = i&31 (channel within the 32-chunk).
//   value = cos(ph[k])*w_real[o][i][k] - sin(ph[k])*w_imag[o][i][k]
// Sized [2][128][128][32] bf16 = 2 MB workspace.
// With this layout a wave's 4 B-fragments for step j are one contiguous 1 KB
// block at  nb*1MB + j*8KB + (wn*64+jn*16+n16)*64B + q*16B  -> 4 coalesced
// global_load_dwordx4 with immediate offsets, straight from L2 (wt resident).
// The e<->channel map matches the A-side LDS layout, so the MFMA contraction
// is unchanged.
// ---------------------------------------------------------------------------
__global__ void __launch_bounds__(256) build_wt_kernel(const float* __restrict__ wr,
                                                       const float* __restrict__ wi,
                                                       const float* __restrict__ ph,
                                                       __bf16* __restrict__ wt) {
  int t = blockIdx.x * 256 + threadIdx.x;   // 65536 threads: one per (o,i)
  int o = t >> 8, i = t & 255;
  const float4* wr4 = (const float4*)(wr + (size_t)(o * CIN_ + i) * K_);
  const float4* wi4 = (const float4*)(wi + (size_t)(o * CIN_ + i) * K_);
  float re[16], im[16];
  #pragma unroll
  for (int v = 0; v < 4; v++) {
    float4 a = wr4[v];
    re[4*v+0]=a.x; re[4*v+1]=a.y; re[4*v+2]=a.z; re[4*v+3]=a.w;
    float4 b = wi4[v];
    im[4*v+0]=b.x; im[4*v+1]=b.y; im[4*v+2]=b.z; im[4*v+3]=b.w;
  }
  const int nb = o >> 7, r = o & 127, ic = i >> 5, e = i & 31;
  __bf16* base = wt + (size_t)nb * (128 * 128 * 32)
                    + (size_t)(ic * 16) * 4096 + r * 32 + e;
  #pragma unroll
  for (int k = 0; k < K_; k++) {
    float p = ph[k];
    base[(size_t)k * 4096] = (__bf16)(cosf(p)*re[k] - sinf(p)*im[k]);
  }
}

// ---------------------------------------------------------------------------
// Main: implicit-GEMM conv, BARRIER-FREE inner loop (round 8).
//
// Rounds 5-7 all tried to hide the per-iter barrier's LDS-read burst and all
// regressed: the 4-wave lockstep structure itself was the residue. This
// round removes its cause. B (2 MB, L2-resident, layout under our control)
// is loaded FRAGMENT-DIRECT from global into registers via the wt3 layout
// above - no Bs LDS, no staging pipeline, NO in-loop barriers. Waves run
// decoupled for 16 consecutive steps; barriers remain only at the 8 As
// restages. Pipe budget per CU-iter-round: MFMA ~1242 cyc (now critical),
// LDS (As reads only) ~800, VMEM/L2 B-traffic 64 KB ~ 49 B/cyc < 56 budget.
//  - bf0/bf1 double-buffered register sets (2-step unrolled body): issue
//    distance ~16 MFMA ~ 310 cyc > 200 cyc L2-hit latency; compiler emits
//    counted vmcnt(4) automatically (4 newer loads outstanding at each use).
//  - B frag addressing: one per-lane byte offset vb; frag jn at +jn*1024
//    (13-bit imm ok); step j at +j*8192.
//  - As: round-4 verified T2 swizzle (conflicts 1.678e7 -> 0) on write+read.
//    Restage every 16 steps: raw barrier (af reads of old tile were consumed
//    by MFMA pre-barrier), direct stage_a, lgkmcnt(0)+barrier.
//  - acc 64 + bf0/bf1 32 + af 16 + addr ~12 = ~124 regs < 128 cap
//    (launch_bounds(256,4)); LDS 9216 B. 4 blocks/CU (VGPR-bound).
//  - s_setprio(1) around MFMA clusters (T5; waves now fully desynced).
// ---------------------------------------------------------------------------
__global__ void __launch_bounds__(256, 4) conv_mfma_kernel(const float* __restrict__ xg,
                                                           const __bf16* __restrict__ wt,
                                                           float* __restrict__ out) {
  __shared__ __align__(16) __bf16 As[144 * 32];       // [row t-local][32 ch] 9216 B

  const int bx = blockIdx.x;
  const int nb = bx & 1;          // o-block 0..1
  const int mb = (bx >> 1) & 15;  // t-block 0..15
  const int b  = bx >> 5;         // batch   0..31

  const int tid  = threadIdx.x;
  const int w    = tid >> 6;
  const int lane = tid & 63;
  const int wm   = w >> 1, wn = w & 1;
  const int n16  = lane & 15, q = lane >> 4;

  const int t0 = mb * 128;
  const int o0 = nb * 128;

  const float* xbase = xg + (size_t)b * (S_ * CIN_);

  // A staging geometry (reg round-trip): thread -> (row sr, 4 fp32 at col sc)
  const int sr = tid >> 3;        // 0..31
  const int sc = (tid & 7) * 4;   // fp32/bf16 col offset (8B chunk; slot = sc>>3)

  // B fragment-direct addressing: wave-local 1KB block per step.
  const char* bb = (const char*)(wt + (size_t)nb * (128 * 128 * 32))
                 + ((wn * 64 + n16) * 32 + q * 8) * 2;

  f32x4 acc[4][4];
  #pragma unroll
  for (int im_ = 0; im_ < 4; im_++)
    #pragma unroll
    for (int in_ = 0; in_ < 4; in_++)
      acc[im_][in_] = {0.f, 0.f, 0.f, 0.f};

  // ---- Stage A for channel group ic: rows 0..143 (x rows t0.., clamped) ----
  // T2 (round-4 verified): 8B chunk (orig col sc) lands at col sc^(((r>>1)&3)<<3).
  auto stage_a = [&](int ic) {
    const float* xcol = xbase + ic * 32 + sc;
    #pragma unroll
    for (int p = 0; p < 4; p++) {
      int r = p * 32 + sr;
      int rg = t0 + r; rg = (rg < S_) ? rg : (S_ - 1);
      float4 v = *(const float4*)(xcol + (size_t)rg * CIN_);
      bf16x4 o4; o4[0]=(__bf16)v.x; o4[1]=(__bf16)v.y; o4[2]=(__bf16)v.z; o4[3]=(__bf16)v.w;
      *(bf16x4*)(As + r * 32 + (sc ^ (((r >> 1) & 3) << 3))) = o4;
    }
    if (tid < 128) {  // tail rows 128..143
      int r = 128 + sr;
      int rg = t0 + r; rg = (rg < S_) ? rg : (S_ - 1);
      float4 v = *(const float4*)(xcol + (size_t)rg * CIN_);
      bf16x4 o4; o4[0]=(__bf16)v.x; o4[1]=(__bf16)v.y; o4[2]=(__bf16)v.z; o4[3]=(__bf16)v.w;
      *(bf16x4*)(As + r * 32 + (sc ^ (((r >> 1) & 3) << 3))) = o4;
    }
  };

  bf16x8 af[4], bf0[4], bf1[4];

  auto read_af = [&](int kp) {      // kp = kk of the target step
    const int aswz = ((kp + n16) >> 1) & 3;   // As row bits[2:1], uniform over jm
    #pragma unroll
    for (int jm = 0; jm < 4; jm++) {
      int row = kp + wm * 64 + jm * 16 + n16;    // A[m=lane&15][k=q*8+j]
      af[jm] = *(const bf16x8*)(As + row * 32 + ((q ^ aswz) * 8));
    }
  };
  auto load_b = [&](bf16x8* dst, int j) {
    const char* p = bb + (size_t)j * 8192;
    #pragma unroll
    for (int jn = 0; jn < 4; jn++)
      dst[jn] = *(const bf16x8*)(p + jn * 1024);
  };

  #define MFMA_CLUSTER(BF)                                                        \
    __builtin_amdgcn_s_setprio(1);                                                \
    _Pragma("unroll")                                                             \
    for (int jm = 0; jm < 4; jm++)                                                \
      _Pragma("unroll")                                                           \
      for (int jn = 0; jn < 4; jn++)                                              \
        acc[jm][jn] = __builtin_amdgcn_mfma_f32_16x16x32_bf16(af[jm], (BF)[jn],   \
                                                              acc[jm][jn], 0, 0, 0); \
    __builtin_amdgcn_s_setprio(0);

  // ---- Prologue: As(ic=0); first B set in flight; publish As. ----
  stage_a(0);
  load_b(bf0, 0);
  asm volatile("s_waitcnt lgkmcnt(0)\n\ts_barrier" ::: "memory");

  #pragma unroll 1
  for (int j = 0; j < 128; j += 2) {
    const int kk = j & 15;

    load_b(bf1, j + 1);                 // issue next step's B (always valid)
    read_af(kk);
    MFMA_CLUSTER(bf0);                  // compiler: vmcnt(4) keeps bf1 in flight

    if (j + 2 < 128) load_b(bf0, j + 2);
    read_af(kk + 1);
    MFMA_CLUSTER(bf1);                  // vmcnt(4) keeps bf0(j+2) in flight

    if (kk == 14 && j + 2 < 128) {
      // ic boundary: every wave consumed its af reads of the old tile in the
      // MFMA above -> raw barrier, direct restage, fence ds_writes, release.
      // (In-flight bf0 global loads target registers, unaffected by barrier.)
      asm volatile("s_barrier" ::: "memory");
      stage_a((j >> 4) + 1);
      asm volatile("s_waitcnt lgkmcnt(0)\n\ts_barrier" ::: "memory");
    }
  }
  #undef MFMA_CLUSTER

  // ---- Epilogue: C/D layout col = lane&15, row = (lane>>4)*4 + reg ----
  float* obase = out + (size_t)b * TOUT_ * COUT_;
  #pragma unroll
  for (int jm = 0; jm < 4; jm++) {
    #pragma unroll
    for (int r = 0; r < 4; r++) {
      int t = t0 + wm * 64 + jm * 16 + q * 4 + r;
      if (t < TOUT_) {
        float* orow = obase + (size_t)t * COUT_ + o0 + wn * 64 + n16;
        #pragma unroll
        for (int jn = 0; jn < 4; jn++)
          orow[jn * 16] = acc[jm][jn][r];
      }
    }
  }
}

// ---------------------------------------------------------------------------
extern "C" void kernel_launch(void* const* d_in, const int* in_sizes, int n_in,
                              void* d_out, int out_size, void* d_ws, size_t ws_size,
                              hipStream_t stream) {
  const float* x  = (const float*)d_in[0];
  const float* wr = (const float*)d_in[1];
  const float* wi = (const float*)d_in[2];
  const float* ph = (const float*)d_in[3];
  float* out = (float*)d_out;

  __bf16* wt = (__bf16*)d_ws;  // 2 MB only

  build_wt_kernel<<<dim3((COUT_ * CIN_) / 256), dim3(256), 0, stream>>>(wr, wi, ph, wt);
  conv_mfma_kernel<<<dim3(B_ * 16 * 2), dim3(256), 0, stream>>>(x, wt, out);
}